// Round 1
// baseline (1302.457 us; speedup 1.0000x reference)
//
#include <hip/hip_runtime.h>

#define E 8
#define T 2048
#define D 1024
#define H 4096

using f32x4 = __attribute__((ext_vector_type(4))) float;
using frag8 = __attribute__((ext_vector_type(8))) short;  // 8 bf16 in 4 VGPRs

typedef unsigned int uint_as3 __attribute__((address_space(3)));
typedef unsigned int uint_as1 __attribute__((address_space(1)));

__device__ __forceinline__ unsigned short f2bf(float f) {
  unsigned int u = __float_as_uint(f);
  u += 0x7fffu + ((u >> 16) & 1u);  // round-to-nearest-even
  return (unsigned short)(u >> 16);
}

__device__ __forceinline__ void gload16(const void* g, void* l) {
  // async global->LDS, 16B per lane; LDS dest = wave-uniform base + lane*16
  __builtin_amdgcn_global_load_lds((const uint_as1*)g, (uint_as3*)l, 16, 0, 0);
}

// Stage one 128-row x 64-col bf16 tile. src points at (row0=0, k0) already;
// ld = row stride in elements. Each wave stages rows [w*32, w*32+32).
__device__ __forceinline__ void stage_tile(const unsigned short* src, int ld,
                                           unsigned short* lds, int w, int lane) {
  int lr = lane >> 3;        // row within 8-row chunk
  int lc = (lane & 7) * 8;   // col offset (elements)
#pragma unroll
  for (int j = 0; j < 4; ++j) {
    int r0 = w * 32 + j * 8;
    const unsigned short* g = src + (size_t)(r0 + lr) * ld + lc;
    unsigned short* l = lds + r0 * 64;  // wave-uniform
    gload16(g, l);
  }
}

// ---------------- pass 0: convert / transpose-convert to bf16 ----------------

__global__ __launch_bounds__(256) void convert_kernel(const float4* __restrict__ in,
                                                      ushort4* __restrict__ out, int n4) {
  int i = blockIdx.x * blockDim.x + threadIdx.x;
  int stride = gridDim.x * blockDim.x;
  for (; i < n4; i += stride) {
    float4 v = in[i];
    ushort4 o;
    o.x = f2bf(v.x); o.y = f2bf(v.y); o.z = f2bf(v.z); o.w = f2bf(v.w);
    out[i] = o;
  }
}

// per-expert [R,C] fp32 -> [C,R] bf16.  grid: (C/32, R/32, E), block (32,8)
__global__ __launch_bounds__(256) void tconv_kernel(const float* __restrict__ in,
                                                    unsigned short* __restrict__ out,
                                                    int R, int C) {
  __shared__ float tile[32][33];
  int e = blockIdx.z;
  const float* src = in + (size_t)e * R * C;
  unsigned short* dst = out + (size_t)e * R * C;
  int c0 = blockIdx.x * 32, r0 = blockIdx.y * 32;
  int tx = threadIdx.x, ty = threadIdx.y;
#pragma unroll
  for (int i = 0; i < 32; i += 8)
    tile[ty + i][tx] = src[(size_t)(r0 + ty + i) * C + c0 + tx];
  __syncthreads();
#pragma unroll
  for (int i = 0; i < 32; i += 8)
    dst[(size_t)(c0 + ty + i) * R + r0 + tx] = f2bf(tile[tx][ty + i]);
}

// ---------------- GEMM1: og = (x@Wfc + bfc) * silu(x@Wg + bg) ----------------
// A = xb [E,T,D] bf16, B^T = wT [E,H,D] bf16. 128x128 tile, BK=64,
// 16x16x32 bf16 MFMA, 4 waves each computing a 64x64 quadrant (two accs).

__global__ __launch_bounds__(256) void gemm1_kernel(
    const unsigned short* __restrict__ xb,
    const unsigned short* __restrict__ wfcT,
    const unsigned short* __restrict__ wgT,
    const float* __restrict__ bfc,
    const float* __restrict__ bgate,
    unsigned short* __restrict__ og) {
  __shared__ unsigned short As[128 * 64];
  __shared__ unsigned short Bf[128 * 64];
  __shared__ unsigned short Bg[128 * 64];

  int bid = blockIdx.x;
  int e = bid >> 9;           // 512 blocks/expert
  int mt = (bid >> 5) & 15;   // T/128 = 16
  int nt = bid & 31;          // H/128 = 32
  int m0 = mt * 128, n0 = nt * 128;

  int tid = threadIdx.x;
  int w = __builtin_amdgcn_readfirstlane(tid >> 6);
  int lane = tid & 63;

  const unsigned short* Abase = xb + (size_t)e * T * D + (size_t)m0 * D;
  const unsigned short* Fbase = wfcT + (size_t)e * H * D + (size_t)n0 * D;
  const unsigned short* Gbase = wgT + (size_t)e * H * D + (size_t)n0 * D;

  f32x4 acc_h[4][4] = {};
  f32x4 acc_g[4][4] = {};

  int wm = (w >> 1) * 64;
  int wn = (w & 1) * 64;
  int col = lane & 15, quad = lane >> 4;

  for (int k0 = 0; k0 < D; k0 += 64) {
    stage_tile(Abase + k0, D, As, w, lane);
    stage_tile(Fbase + k0, D, Bf, w, lane);
    stage_tile(Gbase + k0, D, Bg, w, lane);
    __syncthreads();
#pragma unroll
    for (int kk = 0; kk < 64; kk += 32) {
      frag8 a[4], fb[4], gb[4];
#pragma unroll
      for (int i = 0; i < 4; ++i)
        a[i] = *(const frag8*)&As[(wm + i * 16 + col) * 64 + kk + quad * 8];
#pragma unroll
      for (int i = 0; i < 4; ++i) {
        fb[i] = *(const frag8*)&Bf[(wn + i * 16 + col) * 64 + kk + quad * 8];
        gb[i] = *(const frag8*)&Bg[(wn + i * 16 + col) * 64 + kk + quad * 8];
      }
#pragma unroll
      for (int mi = 0; mi < 4; ++mi)
#pragma unroll
        for (int ni = 0; ni < 4; ++ni) {
          acc_h[mi][ni] = __builtin_amdgcn_mfma_f32_16x16x32_bf16(a[mi], fb[ni], acc_h[mi][ni], 0, 0, 0);
          acc_g[mi][ni] = __builtin_amdgcn_mfma_f32_16x16x32_bf16(a[mi], gb[ni], acc_g[mi][ni], 0, 0, 0);
        }
    }
    __syncthreads();
  }

  // epilogue: bias + silu gate + product, write og bf16
#pragma unroll
  for (int ni = 0; ni < 4; ++ni) {
    int n = n0 + wn + ni * 16 + col;
    float bh = bfc[e * H + n];
    float bg2 = bgate[e * H + n];
#pragma unroll
    for (int mi = 0; mi < 4; ++mi) {
#pragma unroll
      for (int i = 0; i < 4; ++i) {
        int m = m0 + wm + mi * 16 + quad * 4 + i;
        float hv = acc_h[mi][ni][i] + bh;
        float gv = acc_g[mi][ni][i] + bg2;
        float sg = gv / (1.0f + __expf(-gv));
        og[(size_t)e * T * H + (size_t)m * H + n] = f2bf(hv * sg);
      }
    }
  }
}

// ---------------- GEMM2: out = og @ Wproj + bproj (fp32 out) ----------------
// A = og [E,T,H] bf16, B^T = wpT [E,D,H] bf16. K=4096.

__global__ __launch_bounds__(256) void gemm2_kernel(
    const unsigned short* __restrict__ og,
    const unsigned short* __restrict__ wpT,
    const float* __restrict__ bproj,
    float* __restrict__ out) {
  __shared__ unsigned short As[128 * 64];
  __shared__ unsigned short Bs[128 * 64];

  int bid = blockIdx.x;
  int e = bid >> 7;          // 128 blocks/expert
  int mt = (bid >> 3) & 15;  // T/128 = 16
  int nt = bid & 7;          // D/128 = 8
  int m0 = mt * 128, n0 = nt * 128;

  int tid = threadIdx.x;
  int w = __builtin_amdgcn_readfirstlane(tid >> 6);
  int lane = tid & 63;

  const unsigned short* Abase = og + (size_t)e * T * H + (size_t)m0 * H;
  const unsigned short* Bbase = wpT + (size_t)e * D * H + (size_t)n0 * H;

  f32x4 acc[4][4] = {};

  int wm = (w >> 1) * 64;
  int wn = (w & 1) * 64;
  int col = lane & 15, quad = lane >> 4;

  for (int k0 = 0; k0 < H; k0 += 64) {
    stage_tile(Abase + k0, H, As, w, lane);
    stage_tile(Bbase + k0, H, Bs, w, lane);
    __syncthreads();
#pragma unroll
    for (int kk = 0; kk < 64; kk += 32) {
      frag8 a[4], b[4];
#pragma unroll
      for (int i = 0; i < 4; ++i)
        a[i] = *(const frag8*)&As[(wm + i * 16 + col) * 64 + kk + quad * 8];
#pragma unroll
      for (int i = 0; i < 4; ++i)
        b[i] = *(const frag8*)&Bs[(wn + i * 16 + col) * 64 + kk + quad * 8];
#pragma unroll
      for (int mi = 0; mi < 4; ++mi)
#pragma unroll
        for (int ni = 0; ni < 4; ++ni)
          acc[mi][ni] = __builtin_amdgcn_mfma_f32_16x16x32_bf16(a[mi], b[ni], acc[mi][ni], 0, 0, 0);
    }
    __syncthreads();
  }

#pragma unroll
  for (int ni = 0; ni < 4; ++ni) {
    int n = n0 + wn + ni * 16 + col;
    float bb = bproj[e * D + n];
#pragma unroll
    for (int mi = 0; mi < 4; ++mi) {
#pragma unroll
      for (int i = 0; i < 4; ++i) {
        int m = m0 + wm + mi * 16 + quad * 4 + i;
        out[(size_t)e * T * D + (size_t)m * D + n] = acc[mi][ni][i] + bb;
      }
    }
  }
}

// ---------------------------------------------------------------------------

extern "C" void kernel_launch(void* const* d_in, const int* in_sizes, int n_in,
                              void* d_out, int out_size, void* d_ws, size_t ws_size,
                              hipStream_t stream) {
  const float* x = (const float*)d_in[0];
  const float* wfc = (const float*)d_in[1];
  const float* bfc = (const float*)d_in[2];
  const float* wg = (const float*)d_in[3];
  const float* bg = (const float*)d_in[4];
  const float* wp = (const float*)d_in[5];
  const float* bp = (const float*)d_in[6];
  float* out = (float*)d_out;

  char* ws = (char*)d_ws;
  // ws layout (bytes): xb 32MB | wfcT 64MB | wgT 64MB | wpT 64MB | og 128MB
  unsigned short* xb = (unsigned short*)(ws);
  unsigned short* wfcT = (unsigned short*)(ws + 33554432);
  unsigned short* wgT = (unsigned short*)(ws + 100663296);
  unsigned short* wpT = (unsigned short*)(ws + 167772160);
  unsigned short* og = (unsigned short*)(ws + 234881024);

  // x: straight fp32 -> bf16
  convert_kernel<<<2048, 256, 0, stream>>>((const float4*)x, (ushort4*)xb,
                                           (int)((size_t)E * T * D / 4));
  // weights: transpose-convert to B^T bf16 layout [N,K]
  tconv_kernel<<<dim3(H / 32, D / 32, E), dim3(32, 8), 0, stream>>>(wfc, wfcT, D, H);
  tconv_kernel<<<dim3(H / 32, D / 32, E), dim3(32, 8), 0, stream>>>(wg, wgT, D, H);
  tconv_kernel<<<dim3(D / 32, H / 32, E), dim3(32, 8), 0, stream>>>(wp, wpT, H, D);

  gemm1_kernel<<<E * (T / 128) * (H / 128), 256, 0, stream>>>(xb, wfcT, wgT, bfc, bg, og);
  gemm2_kernel<<<E * (T / 128) * (D / 128), 256, 0, stream>>>(og, wpT, bp, out);
}

// Round 2
// 1040.554 us; speedup vs baseline: 1.2517x; 1.2517x over previous
//
#include <hip/hip_runtime.h>

#define E 8
#define T 2048
#define D 1024
#define H 4096

using f32x4 = __attribute__((ext_vector_type(4))) float;
using frag8 = __attribute__((ext_vector_type(8))) short;  // 8 bf16 in 4 VGPRs

typedef unsigned int uint_as3 __attribute__((address_space(3)));
typedef unsigned int uint_as1 __attribute__((address_space(1)));

__device__ __forceinline__ unsigned short f2bf(float f) {
  unsigned int u = __float_as_uint(f);
  u += 0x7fffu + ((u >> 16) & 1u);  // round-to-nearest-even
  return (unsigned short)(u >> 16);
}

__device__ __forceinline__ void gload16(const void* g, void* l) {
  __builtin_amdgcn_global_load_lds((const uint_as1*)g, (uint_as3*)l, 16, 0, 0);
}

// Stage 8 rows x 64 cols bf16 starting at row r0, one full wave (64 lanes x 16B).
// XOR-swizzle: LDS slot (row, cs) holds global chunk cs ^ (row&7). Since the
// LDS dest of global_load_lds is forced to base+lane*16, we permute the GLOBAL
// source chunk per lane instead: lane (lr, cs) fetches chunk cs^lr. The 8
// chunks of one row stay inside the same 128B segment -> still coalesced.
__device__ __forceinline__ void stage8(const unsigned short* src, int ld,
                                       unsigned short* lds, int r0, int lane) {
  int lr = lane >> 3;       // row within the 8-row chunk
  int cs = lane & 7;        // LDS chunk slot
  int gc = cs ^ lr;         // swizzled global chunk
  const unsigned short* g = src + (size_t)(r0 + lr) * ld + gc * 8;
  unsigned short* l = lds + r0 * 64;  // wave-uniform base
  gload16(g, l);
}

// Read a K-contiguous 8-elem bf16 fragment for `row` at element offset chunk*8,
// undoing the swizzle. Bank group = chunk^(row&7): within a quad the 16 lanes
// (consecutive rows) cover all 8 groups twice -> 2-way -> conflict-free (m136).
__device__ __forceinline__ frag8 read_frag(const unsigned short* lds, int row, int chunk) {
  return *(const frag8*)&lds[row * 64 + ((chunk ^ (row & 7)) << 3)];
}

// ---------------- pass 0: convert / transpose-convert to bf16 ----------------

__global__ __launch_bounds__(256) void convert_kernel(const float4* __restrict__ in,
                                                      ushort4* __restrict__ out, int n4) {
  int i = blockIdx.x * blockDim.x + threadIdx.x;
  int stride = gridDim.x * blockDim.x;
  for (; i < n4; i += stride) {
    float4 v = in[i];
    ushort4 o;
    o.x = f2bf(v.x); o.y = f2bf(v.y); o.z = f2bf(v.z); o.w = f2bf(v.w);
    out[i] = o;
  }
}

// per-expert [R,C] fp32 -> [C,R] bf16.  grid: (C/32, R/32, E), block (32,8)
__global__ __launch_bounds__(256) void tconv_kernel(const float* __restrict__ in,
                                                    unsigned short* __restrict__ out,
                                                    int R, int C) {
  __shared__ float tile[32][33];
  int e = blockIdx.z;
  const float* src = in + (size_t)e * R * C;
  unsigned short* dst = out + (size_t)e * R * C;
  int c0 = blockIdx.x * 32, r0 = blockIdx.y * 32;
  int tx = threadIdx.x, ty = threadIdx.y;
#pragma unroll
  for (int i = 0; i < 32; i += 8)
    tile[ty + i][tx] = src[(size_t)(r0 + ty + i) * C + c0 + tx];
  __syncthreads();
#pragma unroll
  for (int i = 0; i < 32; i += 8)
    dst[(size_t)(c0 + ty + i) * R + r0 + tx] = f2bf(tile[tx][ty + i]);
}

// ---------------- GEMM1: og = (x@Wfc + bfc) * silu(x@Wg + bg) ----------------
// A = xb [E,T,D] bf16, B^T = wT [E,H,D] bf16. 128(M)x64(N) tile, BK=64.
// 4 waves; each computes a 64x32 quadrant of BOTH h and g:
// acc = 2*(4x2)*4 = 64 AGPRs (vs 128 before) -> 2 waves/SIMD occupancy.

__global__ __launch_bounds__(256) void gemm1_kernel(
    const unsigned short* __restrict__ xb,
    const unsigned short* __restrict__ wfcT,
    const unsigned short* __restrict__ wgT,
    const float* __restrict__ bfc,
    const float* __restrict__ bgate,
    unsigned short* __restrict__ og) {
  __shared__ unsigned short As[128 * 64];  // 16 KB
  __shared__ unsigned short Bf[64 * 64];   // 8 KB
  __shared__ unsigned short Bg[64 * 64];   // 8 KB

  int bid = blockIdx.x;
  int e = bid >> 10;          // 1024 blocks/expert (16 x 64)
  int mt = (bid >> 6) & 15;   // T/128 = 16
  int nt = bid & 63;          // H/64 = 64
  int m0 = mt * 128, n0 = nt * 64;

  int tid = threadIdx.x;
  int w = __builtin_amdgcn_readfirstlane(tid >> 6);
  int lane = tid & 63;

  const unsigned short* Abase = xb + (size_t)e * T * D + (size_t)m0 * D;
  const unsigned short* Fbase = wfcT + (size_t)e * H * D + (size_t)n0 * D;
  const unsigned short* Gbase = wgT + (size_t)e * H * D + (size_t)n0 * D;

  f32x4 acc_h[4][2] = {};
  f32x4 acc_g[4][2] = {};

  int wm = (w >> 1) * 64;   // 0 or 64
  int wn = (w & 1) * 32;    // 0 or 32
  int col = lane & 15, quad = lane >> 4;

  for (int k0 = 0; k0 < D; k0 += 64) {
#pragma unroll
    for (int j = 0; j < 4; ++j)
      stage8(Abase + k0, D, As, w * 32 + j * 8, lane);
#pragma unroll
    for (int j = 0; j < 2; ++j) {
      stage8(Fbase + k0, D, Bf, w * 16 + j * 8, lane);
      stage8(Gbase + k0, D, Bg, w * 16 + j * 8, lane);
    }
    __syncthreads();
#pragma unroll
    for (int kk = 0; kk < 64; kk += 32) {
      int chunk = (kk >> 3) + quad;
      frag8 a[4], fb[2], gb[2];
#pragma unroll
      for (int i = 0; i < 4; ++i)
        a[i] = read_frag(As, wm + i * 16 + col, chunk);
#pragma unroll
      for (int i = 0; i < 2; ++i) {
        fb[i] = read_frag(Bf, wn + i * 16 + col, chunk);
        gb[i] = read_frag(Bg, wn + i * 16 + col, chunk);
      }
#pragma unroll
      for (int mi = 0; mi < 4; ++mi)
#pragma unroll
        for (int ni = 0; ni < 2; ++ni) {
          acc_h[mi][ni] = __builtin_amdgcn_mfma_f32_16x16x32_bf16(a[mi], fb[ni], acc_h[mi][ni], 0, 0, 0);
          acc_g[mi][ni] = __builtin_amdgcn_mfma_f32_16x16x32_bf16(a[mi], gb[ni], acc_g[mi][ni], 0, 0, 0);
        }
    }
    __syncthreads();
  }

  // epilogue: bias + silu gate + product, write og bf16
#pragma unroll
  for (int ni = 0; ni < 2; ++ni) {
    int n = n0 + wn + ni * 16 + col;
    float bh = bfc[e * H + n];
    float bg2 = bgate[e * H + n];
#pragma unroll
    for (int mi = 0; mi < 4; ++mi) {
#pragma unroll
      for (int i = 0; i < 4; ++i) {
        int m = m0 + wm + mi * 16 + quad * 4 + i;
        float hv = acc_h[mi][ni][i] + bh;
        float gv = acc_g[mi][ni][i] + bg2;
        float sg = gv / (1.0f + __expf(-gv));
        og[(size_t)e * T * H + (size_t)m * H + n] = f2bf(hv * sg);
      }
    }
  }
}

// ---------------- GEMM2: out = og @ Wproj + bproj (fp32 out) ----------------
// A = og [E,T,H] bf16, B^T = wpT [E,D,H] bf16. K=4096. 128x128 tile,
// 4 waves x (64x64): acc 64 AGPRs (m97 shape) + swizzled LDS.

__global__ __launch_bounds__(256) void gemm2_kernel(
    const unsigned short* __restrict__ og,
    const unsigned short* __restrict__ wpT,
    const float* __restrict__ bproj,
    float* __restrict__ out) {
  __shared__ unsigned short As[128 * 64];
  __shared__ unsigned short Bs[128 * 64];

  int bid = blockIdx.x;
  int e = bid >> 7;          // 128 blocks/expert
  int mt = (bid >> 3) & 15;  // T/128 = 16
  int nt = bid & 7;          // D/128 = 8
  int m0 = mt * 128, n0 = nt * 128;

  int tid = threadIdx.x;
  int w = __builtin_amdgcn_readfirstlane(tid >> 6);
  int lane = tid & 63;

  const unsigned short* Abase = og + (size_t)e * T * H + (size_t)m0 * H;
  const unsigned short* Bbase = wpT + (size_t)e * D * H + (size_t)n0 * H;

  f32x4 acc[4][4] = {};

  int wm = (w >> 1) * 64;
  int wn = (w & 1) * 64;
  int col = lane & 15, quad = lane >> 4;

  for (int k0 = 0; k0 < H; k0 += 64) {
#pragma unroll
    for (int j = 0; j < 4; ++j) {
      stage8(Abase + k0, H, As, w * 32 + j * 8, lane);
      stage8(Bbase + k0, H, Bs, w * 32 + j * 8, lane);
    }
    __syncthreads();
#pragma unroll
    for (int kk = 0; kk < 64; kk += 32) {
      int chunk = (kk >> 3) + quad;
      frag8 a[4], b[4];
#pragma unroll
      for (int i = 0; i < 4; ++i)
        a[i] = read_frag(As, wm + i * 16 + col, chunk);
#pragma unroll
      for (int i = 0; i < 4; ++i)
        b[i] = read_frag(Bs, wn + i * 16 + col, chunk);
#pragma unroll
      for (int mi = 0; mi < 4; ++mi)
#pragma unroll
        for (int ni = 0; ni < 4; ++ni)
          acc[mi][ni] = __builtin_amdgcn_mfma_f32_16x16x32_bf16(a[mi], b[ni], acc[mi][ni], 0, 0, 0);
    }
    __syncthreads();
  }

#pragma unroll
  for (int ni = 0; ni < 4; ++ni) {
    int n = n0 + wn + ni * 16 + col;
    float bb = bproj[e * D + n];
#pragma unroll
    for (int mi = 0; mi < 4; ++mi) {
#pragma unroll
      for (int i = 0; i < 4; ++i) {
        int m = m0 + wm + mi * 16 + quad * 4 + i;
        out[(size_t)e * T * D + (size_t)m * D + n] = acc[mi][ni][i] + bb;
      }
    }
  }
}

// ---------------------------------------------------------------------------

extern "C" void kernel_launch(void* const* d_in, const int* in_sizes, int n_in,
                              void* d_out, int out_size, void* d_ws, size_t ws_size,
                              hipStream_t stream) {
  const float* x = (const float*)d_in[0];
  const float* wfc = (const float*)d_in[1];
  const float* bfc = (const float*)d_in[2];
  const float* wg = (const float*)d_in[3];
  const float* bg = (const float*)d_in[4];
  const float* wp = (const float*)d_in[5];
  const float* bp = (const float*)d_in[6];
  float* out = (float*)d_out;

  char* ws = (char*)d_ws;
  // ws layout (bytes): xb 32MB | wfcT 64MB | wgT 64MB | wpT 64MB | og 128MB
  unsigned short* xb = (unsigned short*)(ws);
  unsigned short* wfcT = (unsigned short*)(ws + 33554432);
  unsigned short* wgT = (unsigned short*)(ws + 100663296);
  unsigned short* wpT = (unsigned short*)(ws + 167772160);
  unsigned short* og = (unsigned short*)(ws + 234881024);

  convert_kernel<<<2048, 256, 0, stream>>>((const float4*)x, (ushort4*)xb,
                                           (int)((size_t)E * T * D / 4));
  tconv_kernel<<<dim3(H / 32, D / 32, E), dim3(32, 8), 0, stream>>>(wfc, wfcT, D, H);
  tconv_kernel<<<dim3(H / 32, D / 32, E), dim3(32, 8), 0, stream>>>(wg, wgT, D, H);
  tconv_kernel<<<dim3(D / 32, H / 32, E), dim3(32, 8), 0, stream>>>(wp, wpT, H, D);

  gemm1_kernel<<<E * (T / 128) * (H / 64), 256, 0, stream>>>(xb, wfcT, wgT, bfc, bg, og);
  gemm2_kernel<<<E * (T / 128) * (D / 128), 256, 0, stream>>>(og, wpT, bp, out);
}